// Round 19
// baseline (16049.962 us; speedup 1.0000x reference)
//
#include <hip/hip_runtime.h>
#include <cstdint>

// GRU persistent kernel v17: T=512, B=64, I=512, H=1024, O=512, fp32.
// == v16 (13.35 ms) + issue-early/wait-late on the two per-step coherent
// batch loads, with the 3 x-projection shadow passes redistributed so each
// latency window has compute cover:
//   P1 : vmcnt-consume pending h; r gate; s=r*hloc          -> arrive(A)
//   A2 : z+y from stash (covers barrier A)                  -> wait(A)
//   b  : ISSUE s-loads; XPRE-z(t+1) (covers s latency); vmcnt
//   P2 : candidate + h update                               -> arrive(B)
//   c  : XPRE-h(t+1) (covers barrier B)                     -> wait(B)
//   d  : ISSUE h-loads(t+1); XPRE-r(t+1) (covers h latency) -> loop
// Everything else identical to v16: 256 blk x 512 thr, 128 VGPR, 96 KB
// swizzled weights, xT, sc0/sc1 coherent h/s, relaxed 2-group barrier, hloc.

#define TT 512
#define BB 64
#define II 512
#define HH 1024
#define OO 512
#define NTHR 512

typedef float4 f4;
__device__ __forceinline__ f4 ld4(const float* p){ return *reinterpret_cast<const f4*>(p); }
__device__ __forceinline__ int swz(int k){ return k ^ (((k >> 4) & 7) << 2); }

// ---- coherent (L2-bypass, L3-served) helpers for h/s ----
// issue-only: 16 loads, NO wait. Consumer must WAITALL() before reading d[].
__device__ __forceinline__ void ldc16_issue(const float* p, f4* d){
  asm volatile(
    "global_load_dwordx4 %0,  %16, off sc0 sc1\n\t"
    "global_load_dwordx4 %1,  %16, off offset:256 sc0 sc1\n\t"
    "global_load_dwordx4 %2,  %16, off offset:512 sc0 sc1\n\t"
    "global_load_dwordx4 %3,  %16, off offset:768 sc0 sc1\n\t"
    "global_load_dwordx4 %4,  %16, off offset:1024 sc0 sc1\n\t"
    "global_load_dwordx4 %5,  %16, off offset:1280 sc0 sc1\n\t"
    "global_load_dwordx4 %6,  %16, off offset:1536 sc0 sc1\n\t"
    "global_load_dwordx4 %7,  %16, off offset:1792 sc0 sc1\n\t"
    "global_load_dwordx4 %8,  %16, off offset:2048 sc0 sc1\n\t"
    "global_load_dwordx4 %9,  %16, off offset:2304 sc0 sc1\n\t"
    "global_load_dwordx4 %10, %16, off offset:2560 sc0 sc1\n\t"
    "global_load_dwordx4 %11, %16, off offset:2816 sc0 sc1\n\t"
    "global_load_dwordx4 %12, %16, off offset:3072 sc0 sc1\n\t"
    "global_load_dwordx4 %13, %16, off offset:3328 sc0 sc1\n\t"
    "global_load_dwordx4 %14, %16, off offset:3584 sc0 sc1\n\t"
    "global_load_dwordx4 %15, %16, off offset:3840 sc0 sc1"
    : "=&v"(d[0]),"=&v"(d[1]),"=&v"(d[2]),"=&v"(d[3]),
      "=&v"(d[4]),"=&v"(d[5]),"=&v"(d[6]),"=&v"(d[7]),
      "=&v"(d[8]),"=&v"(d[9]),"=&v"(d[10]),"=&v"(d[11]),
      "=&v"(d[12]),"=&v"(d[13]),"=&v"(d[14]),"=&v"(d[15])
    : "v"(p) : "memory");
}
#define WAITALL() do { asm volatile("s_waitcnt vmcnt(0)" ::: "memory"); \
                       __builtin_amdgcn_sched_barrier(0); } while (0)
__device__ __forceinline__ void ldc16(const float* p, f4* d){
  ldc16_issue(p, d);
  asm volatile("s_waitcnt vmcnt(0)" ::: "memory");
}
__device__ __forceinline__ void stc1(float* p, float v){
  asm volatile("global_store_dword %0, %1, off sc0 sc1" :: "v"(p), "v"(v) : "memory");
}

// ---------------- one-time prep kernels ----------------
__global__ void k_transpose_x(const float* __restrict__ x, float* __restrict__ xT){
  size_t total = (size_t)TT * II * BB;
  for (size_t n = (size_t)blockIdx.x * blockDim.x + threadIdx.x; n < total;
       n += (size_t)gridDim.x * blockDim.x){
    size_t t = n / ((size_t)II * BB);
    size_t rem = n % ((size_t)II * BB);
    size_t i = rem / BB, b = rem % BB;
    xT[n] = x[(t * BB + b) * II + i];
  }
}

__global__ void k_transpose_wx(const float* __restrict__ W, float* __restrict__ WT){
  size_t n = (size_t)blockIdx.x * blockDim.x + threadIdx.x;
  if (n >= (size_t)II * HH) return;
  size_t j = n / II, k = n % II;
  WT[n] = W[k * HH + j];
}

__global__ void k_transpose_h0(const float* __restrict__ st, float* __restrict__ h0){
  size_t n = (size_t)blockIdx.x * blockDim.x + threadIdx.x;
  if (n >= (size_t)HH * BB) return;
  size_t j = n / BB, b = n % BB;
  h0[n] = st[b * HH + j];
}

__global__ void k_init_bars(unsigned* bars){
  if (threadIdx.x < 512) bars[threadIdx.x] = 0;
}

// ------- barrier: per b-half group of 128 blocks; RELAXED atomics only -------
__device__ __forceinline__ void g_arrive(unsigned* bars, int g, int jt, unsigned ep){
  asm volatile("s_waitcnt vmcnt(0)" ::: "memory");   // drain sc1 data stores
  unsigned* leaf = bars + (g * 9 + (jt & 7)) * 16;
  unsigned old = __hip_atomic_fetch_add(leaf, 1u, __ATOMIC_RELAXED, __HIP_MEMORY_SCOPE_AGENT);
  if (old + 1u == ep * 16u)
    __hip_atomic_fetch_add(bars + (g * 9 + 8) * 16, 1u, __ATOMIC_RELAXED, __HIP_MEMORY_SCOPE_AGENT);
}
__device__ __forceinline__ void g_wait(unsigned* bars, int g, unsigned ep){
  unsigned* root = bars + (g * 9 + 8) * 16;
  while (__hip_atomic_load(root, __ATOMIC_RELAXED, __HIP_MEMORY_SCOPE_AGENT) < ep * 8u)
    __builtin_amdgcn_s_sleep(1);
}

// shfl-reduce over the 3 ksec bits inside a wave (lanes 8,16,32)
#define WREDUCE(v) { v += __shfl_xor(v, 8); v += __shfl_xor(v, 16); v += __shfl_xor(v, 32); }

// ---------------- the persistent GRU kernel ----------------
__global__ __launch_bounds__(NTHR, 2) void k_gru(
    const float* __restrict__ xT,
    const float* __restrict__ WxTr, const float* __restrict__ WxTz, const float* __restrict__ WxTh,
    float* __restrict__ h, float* __restrict__ s,
    const float* __restrict__ W_zh, const float* __restrict__ b_z,
    const float* __restrict__ W_rh, const float* __restrict__ b_r,
    const float* __restrict__ W_hh, const float* __restrict__ b_h,
    const float* __restrict__ W_out, const float* __restrict__ b_out,
    float* __restrict__ out, unsigned* __restrict__ bars)
{
  __shared__ float sW[3 * 8 * 1024];   // [0=RH,1=ZH,2=HH][c<8][k swz]  96 KB
  __shared__ float red[8 * 528];       // cross-wave reduce             16.9 KB
  __shared__ float xpre[3][256];       // x-projections (8c x 32b)
  __shared__ float sZ[256];            // z gate
  __shared__ float hloc[16][32];       // block's own h slice (2 KB)
  __shared__ float sBias[32];          // b_r[8] b_z[8] b_h[8] b_out[4]

  const int tid = threadIdx.x;
  const int bid = blockIdx.x;
  const int jt = bid & 127, bhalf = bid >> 7;
  const int j0 = jt * 8, o0 = jt * 4, bbase = bhalf * 32;
  const int jrow = (jt & 1) * 8;

  // ---- prologue: weight slices -> swizzled LDS ----
  #pragma unroll
  for (int kk2 = 0; kk2 < 2; ++kk2){
    const int k = tid * 2 + kk2;           // 0..1023
    f4 vr  = ld4(W_rh + (size_t)k * HH + j0);
    f4 vr2 = ld4(W_rh + (size_t)k * HH + j0 + 4);
    f4 vz  = ld4(W_zh + (size_t)k * HH + j0);
    f4 vz2 = ld4(W_zh + (size_t)k * HH + j0 + 4);
    f4 vh  = ld4(W_hh + (size_t)k * HH + j0);
    f4 vh2 = ld4(W_hh + (size_t)k * HH + j0 + 4);
    const int kx = swz(k);
    float ar[8] = {vr.x,vr.y,vr.z,vr.w,vr2.x,vr2.y,vr2.z,vr2.w};
    float az[8] = {vz.x,vz.y,vz.z,vz.w,vz2.x,vz2.y,vz2.z,vz2.w};
    float ah[8] = {vh.x,vh.y,vh.z,vh.w,vh2.x,vh2.y,vh2.z,vh2.w};
    #pragma unroll
    for (int c = 0; c < 8; ++c){
      sW[0*8192 + c*1024 + kx] = ar[c];
      sW[1*8192 + c*1024 + kx] = az[c];
      sW[2*8192 + c*1024 + kx] = ah[c];
    }
  }
  if (tid < 8){
    sBias[tid]      = b_r[j0 + tid];
    sBias[8 + tid]  = b_z[j0 + tid];
    sBias[16 + tid] = b_h[j0 + tid];
    if (tid < 4) sBias[24 + tid] = b_out[o0 + tid];
  }

  const int bg = tid & 7, b0 = bbase + bg * 4;
  const int ksec = tid >> 3;           // 0..63
  const int wv = tid >> 6;             // wave 0..7
  const bool wr0 = ((tid & 56) == 0);
  const int kh0 = ksec * 16;           // K=1024 / 64
  const int kx0 = ksec * 8;            // K=512  / 64
  const bool own = (ksec == (jt >> 1));
  __syncthreads();

  // single-gate x-projection pass for step tc: writes xpre[g_]
  #define XPRE_G(g_, tc_) do {                                               \
    float aX_[8][4] = {};                                                    \
    const float* xb_ = xT + (size_t)(tc_) * II * BB + kx0 * BB + b0;         \
    const float* Wg_ = ((g_) == 0) ? WxTr : ((g_) == 1) ? WxTz : WxTh;       \
    _Pragma("unroll")                                                        \
    for (int i4 = 0; i4 < 2; ++i4){                                          \
      f4 xv4_[4];                                                            \
      _Pragma("unroll")                                                      \
      for (int kk = 0; kk < 4; ++kk) xv4_[kk] = ld4(xb_ + (i4*4+kk) * BB);   \
      _Pragma("unroll")                                                      \
      for (int c = 0; c < 8; ++c){                                           \
        f4 wf_ = ld4(Wg_ + (size_t)(j0 + c) * II + kx0 + i4*4);              \
        float wvv_[4] = {wf_.x, wf_.y, wf_.z, wf_.w};                        \
        _Pragma("unroll")                                                    \
        for (int kk = 0; kk < 4; ++kk){                                      \
          const f4 xv_ = xv4_[kk];                                           \
          aX_[c][0] = fmaf(wvv_[kk], xv_.x, aX_[c][0]);                      \
          aX_[c][1] = fmaf(wvv_[kk], xv_.y, aX_[c][1]);                      \
          aX_[c][2] = fmaf(wvv_[kk], xv_.z, aX_[c][2]);                      \
          aX_[c][3] = fmaf(wvv_[kk], xv_.w, aX_[c][3]);                      \
        }                                                                    \
      }                                                                      \
    }                                                                        \
    _Pragma("unroll")                                                        \
    for (int c = 0; c < 8; ++c)                                              \
      _Pragma("unroll")                                                      \
      for (int bb = 0; bb < 4; ++bb) WREDUCE(aX_[c][bb]);                    \
    if (wr0)                                                                 \
      _Pragma("unroll")                                                      \
      for (int c = 0; c < 8; ++c)                                            \
        _Pragma("unroll")                                                    \
        for (int bb = 0; bb < 4; ++bb)                                       \
          red[wv*528 + c*32 + bg*4 + bb] = aX_[c][bb];                       \
    __syncthreads();                                                         \
    if (tid < 256){                                                          \
      float sum_ = 0.f;                                                      \
      _Pragma("unroll")                                                      \
      for (int w = 0; w < 8; ++w) sum_ += red[w*528 + tid];                  \
      xpre[g_][tid] = sum_;                                                  \
    }                                                                        \
    __syncthreads();                                                         \
  } while (0)

  f4 st4[16];                          // pending h (issued in slot d / prologue)
  f4 sv16[16];                         // pending s (issued in slot b)

  // ---- step-0 prologue: all three xpre + issue first h-loads ----
  XPRE_G(1, 0);
  XPRE_G(2, 0);
  XPRE_G(0, 0);
  ldc16_issue(h + kh0 * BB + b0, st4);

  for (int t = 0; t < TT; ++t){
    // ================= P1: r gate (pending h -> consume) =================
    WAITALL();                          // st4 valid
    if (own){
      #pragma unroll
      for (int kk = 0; kk < 16; ++kk)
        *reinterpret_cast<f4*>(&hloc[kk][bg*4]) = st4[kk];
    }
    {
      float aR[8][4] = {};
      #pragma unroll
      for (int i4 = 0; i4 < 4; ++i4){
        const int kxc = swz(kh0 + i4*4);
        #pragma unroll
        for (int c = 0; c < 8; ++c){
          f4 wf = *reinterpret_cast<const f4*>(&sW[0*8192 + c*1024 + kxc]);
          float wvv[4] = {wf.x, wf.y, wf.z, wf.w};
          #pragma unroll
          for (int kk = 0; kk < 4; ++kk){
            const f4 hv = st4[i4*4+kk];
            aR[c][0] = fmaf(wvv[kk], hv.x, aR[c][0]);
            aR[c][1] = fmaf(wvv[kk], hv.y, aR[c][1]);
            aR[c][2] = fmaf(wvv[kk], hv.z, aR[c][2]);
            aR[c][3] = fmaf(wvv[kk], hv.w, aR[c][3]);
          }
        }
      }
      #pragma unroll
      for (int c = 0; c < 8; ++c)
        #pragma unroll
        for (int bb = 0; bb < 4; ++bb) WREDUCE(aR[c][bb]);
      if (wr0)
        #pragma unroll
        for (int c = 0; c < 8; ++c)
          #pragma unroll
          for (int bb = 0; bb < 4; ++bb)
            red[wv*528 + c*32 + bg*4 + bb] = aR[c][bb];
    }
    __syncthreads();
    if (tid < 256){
      float sum = 0.f;
      #pragma unroll
      for (int w = 0; w < 8; ++w) sum += red[w*528 + tid];
      const int c = tid >> 5, bl = tid & 31;
      const float v = sum + xpre[0][tid] + sBias[c];
      const float rr = 1.f / (1.f + expf(-v));
      stc1(&s[(j0 + c)*BB + bbase + bl], rr * hloc[jrow + c][bl]);
    }
    __syncthreads();
    if (tid == 0) g_arrive(bars, bhalf, jt, 2*t + 1);

    // ========== A2: z + y_{t-1} from stash (covers barrier A) ==========
    {
      float aZ[8][4] = {};
      float aY[4][4] = {};
      #pragma unroll
      for (int i4 = 0; i4 < 4; ++i4){
        const int kc = kh0 + i4*4;
        const int kxc = swz(kc);
        #pragma unroll
        for (int c = 0; c < 8; ++c){
          f4 wf = *reinterpret_cast<const f4*>(&sW[1*8192 + c*1024 + kxc]);
          float wvv[4] = {wf.x, wf.y, wf.z, wf.w};
          #pragma unroll
          for (int kk = 0; kk < 4; ++kk){
            const f4 hv = st4[i4*4+kk];
            aZ[c][0] = fmaf(wvv[kk], hv.x, aZ[c][0]);
            aZ[c][1] = fmaf(wvv[kk], hv.y, aZ[c][1]);
            aZ[c][2] = fmaf(wvv[kk], hv.z, aZ[c][2]);
            aZ[c][3] = fmaf(wvv[kk], hv.w, aZ[c][3]);
          }
        }
        #pragma unroll
        for (int oc = 0; oc < 4; ++oc){
          f4 wo = ld4(W_out + (size_t)(o0 + oc) * HH + kc);   // L2-hot
          float wvv[4] = {wo.x, wo.y, wo.z, wo.w};
          #pragma unroll
          for (int kk = 0; kk < 4; ++kk){
            const f4 hv = st4[i4*4+kk];
            aY[oc][0] = fmaf(wvv[kk], hv.x, aY[oc][0]);
            aY[oc][1] = fmaf(wvv[kk], hv.y, aY[oc][1]);
            aY[oc][2] = fmaf(wvv[kk], hv.z, aY[oc][2]);
            aY[oc][3] = fmaf(wvv[kk], hv.w, aY[oc][3]);
          }
        }
      }
      #pragma unroll
      for (int c = 0; c < 8; ++c)
        #pragma unroll
        for (int bb = 0; bb < 4; ++bb) WREDUCE(aZ[c][bb]);
      #pragma unroll
      for (int oc = 0; oc < 4; ++oc)
        #pragma unroll
        for (int bb = 0; bb < 4; ++bb) WREDUCE(aY[oc][bb]);
      if (wr0){
        #pragma unroll
        for (int c = 0; c < 8; ++c)
          #pragma unroll
          for (int bb = 0; bb < 4; ++bb)
            red[wv*528 + c*32 + bg*4 + bb] = aZ[c][bb];
        #pragma unroll
        for (int oc = 0; oc < 4; ++oc)
          #pragma unroll
          for (int bb = 0; bb < 4; ++bb)
            red[wv*528 + 256 + oc*32 + bg*4 + bb] = aY[oc][bb];
      }
    }
    __syncthreads();
    if (tid < 256){
      float sum = 0.f;
      #pragma unroll
      for (int w = 0; w < 8; ++w) sum += red[w*528 + tid];
      const int c = tid >> 5;
      sZ[tid] = 1.f / (1.f + expf(-(sum + xpre[1][tid] + sBias[8 + c])));
    } else if (tid < 384){
      const int idx = tid - 256;
      float sum = 0.f;
      #pragma unroll
      for (int w = 0; w < 8; ++w) sum += red[w*528 + tid];
      const int oc = idx >> 5, bl = idx & 31;
      if (t > 0)
        out[((size_t)(t-1)*BB + bbase + bl)*OO + o0 + oc] = sum + sBias[24 + oc];
    }
    if (tid == 0) g_wait(bars, bhalf, 2*t + 1);
    __syncthreads();

    // ===== slot b: issue s-loads; XPRE-z(t+1) covers the latency =====
    ldc16_issue(s + kh0 * BB + b0, sv16);
    if (t + 1 < TT) XPRE_G(1, t + 1);
    WAITALL();                          // sv16 valid

    // ================= P2: candidate + h update =================
    {
      float aH[8][4] = {};
      #pragma unroll
      for (int i4 = 0; i4 < 4; ++i4){
        const int kxc = swz(kh0 + i4*4);
        #pragma unroll
        for (int c = 0; c < 8; ++c){
          f4 wf = *reinterpret_cast<const f4*>(&sW[2*8192 + c*1024 + kxc]);
          float wvv[4] = {wf.x, wf.y, wf.z, wf.w};
          #pragma unroll
          for (int kk = 0; kk < 4; ++kk){
            const f4 sv = sv16[i4*4+kk];
            aH[c][0] = fmaf(wvv[kk], sv.x, aH[c][0]);
            aH[c][1] = fmaf(wvv[kk], sv.y, aH[c][1]);
            aH[c][2] = fmaf(wvv[kk], sv.z, aH[c][2]);
            aH[c][3] = fmaf(wvv[kk], sv.w, aH[c][3]);
          }
        }
      }
      #pragma unroll
      for (int c = 0; c < 8; ++c)
        #pragma unroll
        for (int bb = 0; bb < 4; ++bb) WREDUCE(aH[c][bb]);
      if (wr0)
        #pragma unroll
        for (int c = 0; c < 8; ++c)
          #pragma unroll
          for (int bb = 0; bb < 4; ++bb)
            red[wv*528 + c*32 + bg*4 + bb] = aH[c][bb];
    }
    __syncthreads();
    if (tid < 256){
      float sum = 0.f;
      #pragma unroll
      for (int w = 0; w < 8; ++w) sum += red[w*528 + tid];
      const int c = tid >> 5, bl = tid & 31;
      const float ht = tanhf(sum + xpre[2][tid] + sBias[16 + c]);
      const float z = sZ[tid];
      const float hold = hloc[jrow + c][bl];
      const float hnew = fmaf(z, ht - hold, hold);
      stc1(&h[(j0 + c)*BB + bbase + bl], hnew);
      if (t == TT - 1) out[(size_t)TT*BB*OO + (size_t)(bbase + bl)*HH + j0 + c] = hnew;
    }
    __syncthreads();
    if (tid == 0) g_arrive(bars, bhalf, jt, 2*t + 2);

    // ===== slot c: XPRE-h(t+1) covers barrier B =====
    if (t + 1 < TT) XPRE_G(2, t + 1);
    if (tid == 0) g_wait(bars, bhalf, 2*t + 2);
    __syncthreads();

    // ===== slot d: issue h-loads(t+1); XPRE-r(t+1) covers the latency =====
    if (t + 1 < TT){
      ldc16_issue(h + kh0 * BB + b0, st4);
      XPRE_G(0, t + 1);
    }
  }

  // ================= trailing y_{T-1} from final h =================
  {
    float aY[4][4] = {};
    f4 hv16[16];
    ldc16(h + kh0 * BB + b0, hv16);
    #pragma unroll
    for (int i4 = 0; i4 < 4; ++i4){
      const int kc = kh0 + i4*4;
      #pragma unroll
      for (int oc = 0; oc < 4; ++oc){
        f4 wo = ld4(W_out + (size_t)(o0 + oc) * HH + kc);
        float wvv[4] = {wo.x, wo.y, wo.z, wo.w};
        #pragma unroll
        for (int kk = 0; kk < 4; ++kk){
          const f4 hv = hv16[i4*4+kk];
          aY[oc][0] = fmaf(wvv[kk], hv.x, aY[oc][0]);
          aY[oc][1] = fmaf(wvv[kk], hv.y, aY[oc][1]);
          aY[oc][2] = fmaf(wvv[kk], hv.z, aY[oc][2]);
          aY[oc][3] = fmaf(wvv[kk], hv.w, aY[oc][3]);
        }
      }
    }
    #pragma unroll
    for (int oc = 0; oc < 4; ++oc)
      #pragma unroll
      for (int bb = 0; bb < 4; ++bb) WREDUCE(aY[oc][bb]);
    if (wr0)
      #pragma unroll
      for (int oc = 0; oc < 4; ++oc)
        #pragma unroll
        for (int bb = 0; bb < 4; ++bb)
          red[wv*528 + oc*32 + bg*4 + bb] = aY[oc][bb];
    __syncthreads();
    if (tid < 128){
      float sum = 0.f;
      #pragma unroll
      for (int w = 0; w < 8; ++w) sum += red[w*528 + tid];
      const int oc = tid >> 5, bl = tid & 31;
      out[((size_t)(TT-1)*BB + bbase + bl)*OO + o0 + oc] = sum + sBias[24 + oc];
    }
  }
  #undef XPRE_G
}

// ---------------- host ----------------
extern "C" void kernel_launch(void* const* d_in, const int* in_sizes, int n_in,
                              void* d_out, int out_size, void* d_ws, size_t ws_size,
                              hipStream_t stream) {
  const float* x     = (const float*)d_in[0];
  const float* st    = (const float*)d_in[1];
  const float* W_zh  = (const float*)d_in[2];
  const float* W_zx  = (const float*)d_in[3];
  const float* b_z   = (const float*)d_in[4];
  const float* W_rh  = (const float*)d_in[5];
  const float* W_rx  = (const float*)d_in[6];
  const float* b_r   = (const float*)d_in[7];
  const float* W_hh  = (const float*)d_in[8];
  const float* W_hx  = (const float*)d_in[9];
  const float* b_h   = (const float*)d_in[10];
  const float* W_out = (const float*)d_in[11];
  const float* b_out = (const float*)d_in[12];
  float* out = (float*)d_out;
  float* ws  = (float*)d_ws;

  const size_t xT_sz = (size_t)TT * II * BB;   // 16,777,216
  const size_t wx_sz = (size_t)II * HH;        //    524,288
  const size_t h_sz  = (size_t)HH * BB;        //     65,536
  const size_t need  = (xT_sz + 3*wx_sz + 2*h_sz) * sizeof(float) + 512*sizeof(unsigned);
  if (ws_size < need) return;

  float* xT   = ws;
  float* WxTr = xT + xT_sz;
  float* WxTz = WxTr + wx_sz;
  float* WxTh = WxTz + wx_sz;
  float* h    = WxTh + wx_sz;
  float* s    = h + h_sz;
  unsigned* bars = (unsigned*)(s + h_sz);

  k_transpose_x <<<8192, 256, 0, stream>>>(x, xT);
  k_transpose_wx<<<2048, 256, 0, stream>>>(W_rx, WxTr);
  k_transpose_wx<<<2048, 256, 0, stream>>>(W_zx, WxTz);
  k_transpose_wx<<<2048, 256, 0, stream>>>(W_hx, WxTh);
  k_transpose_h0<<< 256, 256, 0, stream>>>(st, h);
  k_init_bars   <<<   1, 512, 0, stream>>>(bars);

  k_gru<<<256, NTHR, 0, stream>>>(xT, WxTr, WxTz, WxTh, h, s,
                                  W_zh, b_z, W_rh, b_r, W_hh, b_h,
                                  W_out, b_out, out, bars);
}